// Round 1
// baseline (3314.283 us; speedup 1.0000x reference)
//
#include <hip/hip_runtime.h>
#include <hip/hip_bf16.h>

typedef _Float16 half8 __attribute__((ext_vector_type(8)));
typedef float floatx4 __attribute__((ext_vector_type(4)));

__device__ __constant__ float NF4_TAB[16] = {
    -1.0f, -0.6961928009986877f, -0.5250730514526367f, -0.39491748809814453f,
    -0.28444138169288635f, -0.18477343022823334f, -0.09105003625154495f, 0.0f,
    0.07958029955625534f, 0.16093020141124725f, 0.24611230194568634f,
    0.33791524171829224f, 0.44070982933044434f, 0.5626170039176941f,
    0.7229568362236023f, 1.0f};

typedef __attribute__((address_space(3))) void lds_t;
typedef __attribute__((address_space(1))) void gbl_t;

__device__ __forceinline__ void gload16(const void* g, void* l) {
  __builtin_amdgcn_global_load_lds((gbl_t*)g, (lds_t*)l, 16, 0, 0);
}

// ---------------- x f32 -> f16 ----------------
__global__ void cvt_f32_to_f16(const float* __restrict__ in,
                               _Float16* __restrict__ out, int total8) {
  int stride = gridDim.x * blockDim.x;
  for (int i = blockIdx.x * blockDim.x + threadIdx.x; i < total8; i += stride) {
    long e = (long)i * 8;
    const float4* ip = reinterpret_cast<const float4*>(in + e);
    float4 a = ip[0], b = ip[1];
    half8 o;
    o[0] = (_Float16)a.x; o[1] = (_Float16)a.y;
    o[2] = (_Float16)a.z; o[3] = (_Float16)a.w;
    o[4] = (_Float16)b.x; o[5] = (_Float16)b.y;
    o[6] = (_Float16)b.z; o[7] = (_Float16)b.w;
    *reinterpret_cast<half8*>(out + e) = o;
  }
}

// ---------------- NF4 dequant: codes[R,C] + scales[R,C/64] -> f16 [R,C] ----
__global__ void dequant_nf4(const int* __restrict__ codes,
                            const float* __restrict__ scales,
                            _Float16* __restrict__ out,
                            int total8, int C, int CB) {
  __shared__ float lut[16];
  if (threadIdx.x < 16) lut[threadIdx.x] = NF4_TAB[threadIdx.x];
  __syncthreads();
  int stride = gridDim.x * blockDim.x;
  for (int i = blockIdx.x * blockDim.x + threadIdx.x; i < total8; i += stride) {
    long e = (long)i * 8;
    int row = (int)(e / C);
    int col = (int)(e - (long)row * C);
    float sc = scales[row * CB + (col >> 6)];
    const int4* cp = reinterpret_cast<const int4*>(codes + e);
    int4 c0 = cp[0];
    int4 c1 = cp[1];
    half8 o;
    o[0] = (_Float16)(lut[c0.x & 15] * sc);
    o[1] = (_Float16)(lut[c0.y & 15] * sc);
    o[2] = (_Float16)(lut[c0.z & 15] * sc);
    o[3] = (_Float16)(lut[c0.w & 15] * sc);
    o[4] = (_Float16)(lut[c1.x & 15] * sc);
    o[5] = (_Float16)(lut[c1.y & 15] * sc);
    o[6] = (_Float16)(lut[c1.z & 15] * sc);
    o[7] = (_Float16)(lut[c1.w & 15] * sc);
    *reinterpret_cast<half8*>(out + e) = o;
  }
}

// ---------------- GEMM1: h = silu(x Wg^T) * (x Wu^T), f16 out ----------------
// X [8192,4096], Wg/Wu [11008,4096] row-major (K contiguous both) -> H [8192,11008]
__global__ __launch_bounds__(256, 2) void gemm_gateup(
    const _Float16* __restrict__ X,
    const _Float16* __restrict__ Wg,
    const _Float16* __restrict__ Wu,
    _Float16* __restrict__ H) {
  constexpr int K = 4096;
  constexpr long M = 11008;
  __shared__ __align__(16) _Float16 sA[128][32];
  __shared__ __align__(16) _Float16 sG[128][32];
  __shared__ __align__(16) _Float16 sU[128][32];

  const int t = threadIdx.x;
  const int lane = t & 63, wave = t >> 6;
  const int wr = wave >> 1, wc = wave & 1;
  const int br = blockIdx.y, bc = blockIdx.x;

  const int srow = t >> 2;         // 0..63
  const int scol = (t & 3) * 8;    // 0,8,16,24

  const _Float16* pA = X + (long)(br * 128 + srow) * K + scol;
  const _Float16* pG = Wg + (long)(bc * 128 + srow) * K + scol;
  const _Float16* pU = Wu + (long)(bc * 128 + srow) * K + scol;

  _Float16* dA = &sA[srow][scol];  // == linear t*16 bytes
  _Float16* dG = &sG[srow][scol];
  _Float16* dU = &sU[srow][scol];

  floatx4 accG[4][4] = {};
  floatx4 accU[4][4] = {};

  for (int kk = 0; kk < K; kk += 32) {
    gload16(pA, dA);
    gload16(pA + (long)64 * K, dA + 64 * 32);
    gload16(pG, dG);
    gload16(pG + (long)64 * K, dG + 64 * 32);
    gload16(pU, dU);
    gload16(pU + (long)64 * K, dU + 64 * 32);
    pA += 32; pG += 32; pU += 32;
    __syncthreads();

    const int kq = (lane >> 4) * 8;
    const int rA = wr * 64 + (lane & 15);
    const int rB = wc * 64 + (lane & 15);
    half8 a[4], bg[4], bu[4];
#pragma unroll
    for (int i = 0; i < 4; ++i) {
      a[i]  = *reinterpret_cast<const half8*>(&sA[rA + 16 * i][kq]);
      bg[i] = *reinterpret_cast<const half8*>(&sG[rB + 16 * i][kq]);
      bu[i] = *reinterpret_cast<const half8*>(&sU[rB + 16 * i][kq]);
    }
#pragma unroll
    for (int i = 0; i < 4; ++i) {
#pragma unroll
      for (int j = 0; j < 4; ++j) {
        accG[i][j] = __builtin_amdgcn_mfma_f32_16x16x32_f16(a[i], bg[j], accG[i][j], 0, 0, 0);
        accU[i][j] = __builtin_amdgcn_mfma_f32_16x16x32_f16(a[i], bu[j], accU[i][j], 0, 0, 0);
      }
    }
    __syncthreads();
  }

  // epilogue: h = silu(g)*u, C/D layout col=lane&15, row=(lane>>4)*4+ii
  const int tr0 = br * 128 + wr * 64 + (lane >> 4) * 4;
  const int mc0 = bc * 128 + wc * 64 + (lane & 15);
#pragma unroll
  for (int i = 0; i < 4; ++i) {
#pragma unroll
    for (int j = 0; j < 4; ++j) {
#pragma unroll
      for (int ii = 0; ii < 4; ++ii) {
        float g = accG[i][j][ii];
        float u = accU[i][j][ii];
        float s = g / (1.0f + __expf(-g));
        H[(long)(tr0 + i * 16 + ii) * M + (mc0 + j * 16)] = (_Float16)(s * u);
      }
    }
  }
}

// ---------------- GEMM2: out = h Wd^T, f32 out ----------------
// H [8192,11008], Wd [4096,11008] row-major -> O [8192,4096] f32
__global__ __launch_bounds__(256, 2) void gemm_down(
    const _Float16* __restrict__ Hm,
    const _Float16* __restrict__ Wd,
    float* __restrict__ O) {
  constexpr int K = 11008;
  constexpr long N = 4096;
  __shared__ __align__(16) _Float16 sA[128][32];
  __shared__ __align__(16) _Float16 sB[128][32];

  const int t = threadIdx.x;
  const int lane = t & 63, wave = t >> 6;
  const int wr = wave >> 1, wc = wave & 1;
  const int br = blockIdx.y, bc = blockIdx.x;

  const int srow = t >> 2;
  const int scol = (t & 3) * 8;

  const _Float16* pA = Hm + (long)(br * 128 + srow) * K + scol;
  const _Float16* pB = Wd + (long)(bc * 128 + srow) * K + scol;

  _Float16* dA = &sA[srow][scol];
  _Float16* dB = &sB[srow][scol];

  floatx4 acc[4][4] = {};

  for (int kk = 0; kk < K; kk += 32) {
    gload16(pA, dA);
    gload16(pA + (long)64 * K, dA + 64 * 32);
    gload16(pB, dB);
    gload16(pB + (long)64 * K, dB + 64 * 32);
    pA += 32; pB += 32;
    __syncthreads();

    const int kq = (lane >> 4) * 8;
    const int rA = wr * 64 + (lane & 15);
    const int rB = wc * 64 + (lane & 15);
    half8 a[4], b[4];
#pragma unroll
    for (int i = 0; i < 4; ++i) {
      a[i] = *reinterpret_cast<const half8*>(&sA[rA + 16 * i][kq]);
      b[i] = *reinterpret_cast<const half8*>(&sB[rB + 16 * i][kq]);
    }
#pragma unroll
    for (int i = 0; i < 4; ++i) {
#pragma unroll
      for (int j = 0; j < 4; ++j) {
        acc[i][j] = __builtin_amdgcn_mfma_f32_16x16x32_f16(a[i], b[j], acc[i][j], 0, 0, 0);
      }
    }
    __syncthreads();
  }

  const int tr0 = br * 128 + wr * 64 + (lane >> 4) * 4;
  const int dc0 = bc * 128 + wc * 64 + (lane & 15);
#pragma unroll
  for (int i = 0; i < 4; ++i) {
#pragma unroll
    for (int j = 0; j < 4; ++j) {
#pragma unroll
      for (int ii = 0; ii < 4; ++ii) {
        O[(long)(tr0 + i * 16 + ii) * N + (dc0 + j * 16)] = acc[i][j][ii];
      }
    }
  }
}

extern "C" void kernel_launch(void* const* d_in, const int* in_sizes, int n_in,
                              void* d_out, int out_size, void* d_ws, size_t ws_size,
                              hipStream_t stream) {
  const float* x           = (const float*)d_in[0];
  const int*   gate_codes  = (const int*)d_in[1];
  const float* gate_scales = (const float*)d_in[2];
  const int*   up_codes    = (const int*)d_in[3];
  const float* up_scales   = (const float*)d_in[4];
  const int*   down_codes  = (const int*)d_in[5];
  const float* down_scales = (const float*)d_in[6];
  float* out = (float*)d_out;

  const long T = 8192, HD = 4096, M = 11008;

  // ws layout (fp16): x16 [T,HD] | Wa [M,HD] | Wb [M,HD] | h16 [T,M]
  char* ws = (char*)d_ws;
  _Float16* x16 = (_Float16*)ws;
  _Float16* Wa  = (_Float16*)(ws + T * HD * 2);
  _Float16* Wb  = (_Float16*)(ws + T * HD * 2 + M * HD * 2);
  _Float16* h16 = (_Float16*)(ws + T * HD * 2 + 2 * M * HD * 2);

  cvt_f32_to_f16<<<2048, 256, 0, stream>>>(x, x16, (int)(T * HD / 8));
  dequant_nf4<<<2048, 256, 0, stream>>>(gate_codes, gate_scales, Wa,
                                        (int)(M * HD / 8), (int)HD, (int)(HD / 64));
  dequant_nf4<<<2048, 256, 0, stream>>>(up_codes, up_scales, Wb,
                                        (int)(M * HD / 8), (int)HD, (int)(HD / 64));

  dim3 g1((unsigned)(M / 128), (unsigned)(T / 128));
  gemm_gateup<<<g1, 256, 0, stream>>>(x16, Wa, Wb, h16);

  // reuse Wa for down weights
  dequant_nf4<<<2048, 256, 0, stream>>>(down_codes, down_scales, Wa,
                                        (int)(HD * M / 8), (int)M, (int)(M / 64));

  dim3 g2((unsigned)(HD / 128), (unsigned)(T / 128));
  gemm_down<<<g2, 256, 0, stream>>>(h16, Wa, out);
}